// Round 10
// baseline (420.888 us; speedup 1.0000x reference)
//
#include <hip/hip_runtime.h>

// MetaLayer: edge MLP + mean-aggregate + node MLP. fp32 in/out, int32 idx.
// R9 lesson: removing atomics halved edge_mlp (268->158us) but CSR gather in
// node cost more than it saved (total 415). R10: dst-SORTED edge processing
// (via eidx) + block-level segmented reduction -> ~6M atomics (was 51M),
// node_mlp reads contiguous agg. eout written at original edge ids.

typedef __attribute__((ext_vector_type(8))) short bf16x8;   // MFMA A/B frag
typedef __attribute__((ext_vector_type(4))) float f4;       // MFMA C/D frag
typedef __attribute__((ext_vector_type(8))) unsigned short us8;
typedef __attribute__((ext_vector_type(4))) unsigned short us4;

constexpr int NN  = 50000;
constexpr int NE  = 800000;
constexpr int FN  = 64;
constexpr int FE  = 64;
constexpr int HID = 128;
constexpr int K1  = 2 * FN + FE; // 192
constexpr int K2  = FN + FE;     // 128

__device__ __forceinline__ unsigned short f2b(float f) {
  union { float f; unsigned int i; } v; v.f = f;
  unsigned int r = v.i + 0x7FFFu + ((v.i >> 16) & 1u);
  return (unsigned short)(r >> 16);
}
__device__ __forceinline__ void cvt16(const f4* __restrict__ p, unsigned short* dst) {
  f4 a = p[0], b = p[1], c = p[2], d = p[3];
  us8 o0, o1;
#pragma unroll
  for (int j = 0; j < 4; j++) {
    o0[j] = f2b(a[j]); o0[4 + j] = f2b(b[j]);
    o1[j] = f2b(c[j]); o1[4 + j] = f2b(d[j]);
  }
  *(us8*)dst = o0; *(us8*)(dst + 8) = o1;
}
__device__ __forceinline__ f4 MF(bf16x8 a, bf16x8 b, f4 c) {
  return __builtin_amdgcn_mfma_f32_16x16x32_bf16(a, b, c, 0, 0, 0);
}

__global__ void zero_kernel(float* __restrict__ p, int n) {
  int i = blockIdx.x * 256 + threadIdx.x;
  if (i < n) p[i] = 0.f;
}
__global__ void zeroi_kernel(int* __restrict__ p, int n) {
  int i = blockIdx.x * 256 + threadIdx.x;
  if (i < n) p[i] = 0;
}

__global__ void hist_kernel(const int* __restrict__ ei, int* __restrict__ cnt_i) {
  int e = blockIdx.x * 256 + threadIdx.x;
  if (e < NE) atomicAdd(&cnt_i[ei[NE + e]], 1);
}

// single-block exclusive scan over cnt_i[NN] -> off[NN+1], cur[NN]=off copy
__global__ __launch_bounds__(256) void scan_kernel(
    const int* __restrict__ cnt_i, int* __restrict__ off, int* __restrict__ cur) {
  __shared__ int sums[256];
  const int t = threadIdx.x;
  const int CH = (NN + 255) / 256; // 196
  const int base = t * CH;
  const int end  = min(base + CH, NN);
  int s = 0;
  for (int i = base; i < end; i++) s += cnt_i[i];
  sums[t] = s;
  __syncthreads();
  if (t == 0) { int r = 0; for (int i = 0; i < 256; i++) { int v = sums[i]; sums[i] = r; r += v; } }
  __syncthreads();
  int run = sums[t];
  for (int i = base; i < end; i++) { off[i] = run; cur[i] = run; run += cnt_i[i]; }
  if (t == 255) off[NN] = NE;
}

__global__ void scatter_kernel(const int* __restrict__ ei, int* __restrict__ cur,
                               int* __restrict__ eidx) {
  int e = blockIdx.x * 256 + threadIdx.x;
  if (e < NE) {
    const int c = ei[NE + e];
    const int p = atomicAdd(&cur[c], 1);
    eidx[p] = e;
  }
}

// pack W[K][N] fp32 -> frag order [kstep][ntile][lane][8] bf16.
__global__ void pack_w(const float* __restrict__ W, unsigned short* __restrict__ P,
                       int N, int total) {
  int idx = blockIdx.x * 256 + threadIdx.x;
  if (idx >= total) return;
  const int l  = idx & 63;
  const int nt = (idx >> 6) % (N >> 4);
  const int s  = idx / ((N >> 4) << 6);
  const int col = nt * 16 + (l & 15);
  const int k0  = s * 32 + (l >> 4) * 8;
  us8 o;
#pragma unroll
  for (int j = 0; j < 8; j++) o[j] = f2b(W[(size_t)(k0 + j) * N + col]);
  *(us8*)(P + (size_t)idx * 8) = o;
}

// ---- edge MLP (MFMA): 64 dst-sorted edges/block, 4 waves.
// sH and sOut alias sA. Segmented-reduction aggregation (few atomics).
__global__ __launch_bounds__(256) void edge_mlp(
    const float* __restrict__ x, const int* __restrict__ ei,
    const float* __restrict__ ea, const int* __restrict__ eidx,
    const unsigned short* __restrict__ P1, const float* __restrict__ be1,
    const unsigned short* __restrict__ P2, const float* __restrict__ be2,
    float* __restrict__ eout, float* __restrict__ agg) {
  __shared__ unsigned short sA[64][200]; // 25.6KB; 400B stride
  __shared__ int sC[64];   // dst node per sorted slot
  __shared__ int sEd[64];  // original edge id per sorted slot
  unsigned short (*sH)[136] = (unsigned short(*)[136])&sA[0][0]; // alias
  float (*sOut)[68]         = (float(*)[68])&sA[0][0];           // alias, 17.4KB
  const int tid = threadIdx.x;
  const int sp0 = blockIdx.x * 64;

  { // stage gathered inputs (sorted order) -> bf16 LDS
    const int el = tid >> 2, q = tid & 3;
    const int ge = eidx[sp0 + el];
    const int r = ei[ge], c = ei[NE + ge];
    if (q == 0) { sC[el] = c; sEd[el] = ge; }
    cvt16((const f4*)(x + (size_t)r * FN + q * 16), &sA[el][q * 16]);
    cvt16((const f4*)(x + (size_t)c * FN + q * 16), &sA[el][64 + q * 16]);
    cvt16((const f4*)(ea + (size_t)ge * FE + q * 16), &sA[el][128 + q * 16]);
  }
  __syncthreads();

  const int wave = tid >> 6, lane = tid & 63;
  const int mrow = lane & 15, kq = lane >> 4;

  // GEMM1: [64x192]@[192x128], wave -> ntiles {2w,2w+1}
  f4 acc[4][2];
#pragma unroll
  for (int m = 0; m < 4; m++) { acc[m][0] = (f4)0.f; acc[m][1] = (f4)0.f; }
  const int nt0 = wave * 2;
#pragma unroll
  for (int s = 0; s < 6; s++) {
    bf16x8 b0 = *(const bf16x8*)(P1 + (((size_t)s * 8 + nt0)     * 64 + lane) * 8);
    bf16x8 b1 = *(const bf16x8*)(P1 + (((size_t)s * 8 + nt0 + 1) * 64 + lane) * 8);
#pragma unroll
    for (int m = 0; m < 4; m++) {
      bf16x8 a = *(const bf16x8*)&sA[m * 16 + mrow][s * 32 + kq * 8];
      acc[m][0] = MF(a, b0, acc[m][0]);
      acc[m][1] = MF(a, b1, acc[m][1]);
    }
  }
  __syncthreads(); // sA reads done before alias overwrite

  { // bias + relu -> sH. D: row=(lane>>4)*4+i, col=lane&15
    const int c0 = nt0 * 16 + mrow, c1 = c0 + 16;
    const float bb0 = be1[c0], bb1 = be1[c1];
    const int rb = kq * 4;
#pragma unroll
    for (int m = 0; m < 4; m++)
#pragma unroll
      for (int i = 0; i < 4; i++) {
        sH[m * 16 + rb + i][c0] = f2b(fmaxf(acc[m][0][i] + bb0, 0.f));
        sH[m * 16 + rb + i][c1] = f2b(fmaxf(acc[m][1][i] + bb1, 0.f));
      }
  }
  __syncthreads();

  // GEMM2: [64x128]@[128x64], wave -> ntile w
  f4 a2[4];
#pragma unroll
  for (int m = 0; m < 4; m++) a2[m] = (f4)0.f;
#pragma unroll
  for (int s = 0; s < 4; s++) {
    bf16x8 b = *(const bf16x8*)(P2 + (((size_t)s * 4 + wave) * 64 + lane) * 8);
#pragma unroll
    for (int m = 0; m < 4; m++) {
      bf16x8 a = *(const bf16x8*)&sH[m * 16 + mrow][s * 32 + kq * 8];
      a2[m] = MF(a, b, a2[m]);
    }
  }
  __syncthreads(); // sH reads done before sOut overwrite

  { // epilogue: bias; direct scattered eout write (orig id) + sOut for reduce
    const int col = wave * 16 + mrow;
    const float bb = be2[col];
    const int rb = kq * 4;
#pragma unroll
    for (int m = 0; m < 4; m++)
#pragma unroll
      for (int i = 0; i < 4; i++) {
        const int er = m * 16 + rb + i;
        const float v = a2[m][i] + bb;
        sOut[er][col] = v;
        eout[(size_t)sEd[er] * FE + col] = v;
      }
  }
  __syncthreads();

  { // segmented reduction over sorted dst runs; one atomic per run per col
    const int col = tid & 63, seg = tid >> 6; // 4 segs x 16 rows
    int d = sC[seg * 16];
    float s = 0.f;
#pragma unroll
    for (int j = 0; j < 16; j++) {
      const int er = seg * 16 + j;
      const int dj = sC[er];
      if (dj != d) { atomicAdd(&agg[(size_t)d * FE + col], s); s = 0.f; d = dj; }
      s += sOut[er][col];
    }
    atomicAdd(&agg[(size_t)d * FE + col], s);
  }
}

// ---- node MLP (MFMA): 64 nodes/block, 4 waves. Contiguous agg + cnt_i.
__global__ __launch_bounds__(256) void node_mlp(
    const float* __restrict__ x, const float* __restrict__ agg,
    const int* __restrict__ cnt_i,
    const unsigned short* __restrict__ P1, const float* __restrict__ bn1,
    const unsigned short* __restrict__ P2, const float* __restrict__ bn2,
    float* __restrict__ xout) {
  __shared__ unsigned short sA[64][136]; // 17.4KB; 272B stride
  unsigned short (*sH)[136] = (unsigned short(*)[136])&sA[0][0]; // alias
  const int tid = threadIdx.x;
  const int n0  = blockIdx.x * 64;

  { // stage: 4 threads/node; q<2: x halves; q>=2: agg halves (mean)
    const int nl = tid >> 2, q = tid & 3;
    const int gn = n0 + nl;
    if (gn < NN) {
      if (q < 2) {
        cvt16((const f4*)(x + (size_t)gn * FN + q * 32),      &sA[nl][q * 32]);
        cvt16((const f4*)(x + (size_t)gn * FN + q * 32 + 16), &sA[nl][q * 32 + 16]);
      } else {
        const float inv = 1.0f / fmaxf((float)cnt_i[gn], 1.0f);
        const int q2 = q - 2;
        const f4* pa = (const f4*)(agg + (size_t)gn * FE + q2 * 32);
#pragma unroll
        for (int seg = 0; seg < 8; seg++) {
          f4 a = pa[seg];
          us4 o;
#pragma unroll
          for (int j = 0; j < 4; j++) o[j] = f2b(a[j] * inv);
          *(us4*)&sA[nl][64 + q2 * 32 + seg * 4] = o;
        }
      }
    } else {
      us8 z = (us8)0;
#pragma unroll
      for (int sgi = 0; sgi < 4; sgi++) *(us8*)&sA[nl][q * 32 + sgi * 8] = z;
    }
  }
  __syncthreads();

  const int wave = tid >> 6, lane = tid & 63;
  const int mrow = lane & 15, kq = lane >> 4;

  // GEMM1: [64x128]@[128x128]
  f4 acc[4][2];
#pragma unroll
  for (int m = 0; m < 4; m++) { acc[m][0] = (f4)0.f; acc[m][1] = (f4)0.f; }
  const int nt0 = wave * 2;
#pragma unroll
  for (int s = 0; s < 4; s++) {
    bf16x8 b0 = *(const bf16x8*)(P1 + (((size_t)s * 8 + nt0)     * 64 + lane) * 8);
    bf16x8 b1 = *(const bf16x8*)(P1 + (((size_t)s * 8 + nt0 + 1) * 64 + lane) * 8);
#pragma unroll
    for (int m = 0; m < 4; m++) {
      bf16x8 a = *(const bf16x8*)&sA[m * 16 + mrow][s * 32 + kq * 8];
      acc[m][0] = MF(a, b0, acc[m][0]);
      acc[m][1] = MF(a, b1, acc[m][1]);
    }
  }
  __syncthreads();

  {
    const int c0 = nt0 * 16 + mrow, c1 = c0 + 16;
    const float bb0 = bn1[c0], bb1 = bn1[c1];
    const int rb = kq * 4;
#pragma unroll
    for (int m = 0; m < 4; m++)
#pragma unroll
      for (int i = 0; i < 4; i++) {
        sH[m * 16 + rb + i][c0] = f2b(fmaxf(acc[m][0][i] + bb0, 0.f));
        sH[m * 16 + rb + i][c1] = f2b(fmaxf(acc[m][1][i] + bb1, 0.f));
      }
  }
  __syncthreads();

  // GEMM2: [64x128]@[128x64]
  f4 a2[4];
#pragma unroll
  for (int m = 0; m < 4; m++) a2[m] = (f4)0.f;
#pragma unroll
  for (int s = 0; s < 4; s++) {
    bf16x8 b = *(const bf16x8*)(P2 + (((size_t)s * 4 + wave) * 64 + lane) * 8);
#pragma unroll
    for (int m = 0; m < 4; m++) {
      bf16x8 a = *(const bf16x8*)&sH[m * 16 + mrow][s * 32 + kq * 8];
      a2[m] = MF(a, b, a2[m]);
    }
  }
  {
    const int col = wave * 16 + mrow;
    const float bb = bn2[col];
    const int rb = kq * 4;
#pragma unroll
    for (int m = 0; m < 4; m++)
#pragma unroll
      for (int i = 0; i < 4; i++) {
        const int gn = n0 + m * 16 + rb + i;
        if (gn < NN) xout[(size_t)gn * FN + col] = a2[m][i] + bb;
      }
  }
}

extern "C" void kernel_launch(void* const* d_in, const int* in_sizes, int n_in,
                              void* d_out, int out_size, void* d_ws, size_t ws_size,
                              hipStream_t stream) {
  if (n_in != 11) return;
  if (in_sizes[0] != NN * FN) return;
  if (in_sizes[1] != 2 * NE) return;
  if (in_sizes[2] != NE * FE) return;
  if (out_size != NN * FN + NE * FE) return;
  // ws: agg 12.8MB + packed W 114.7KB + cnt/off/cur/eidx ints = ~16.7MB
  if (ws_size < (size_t)NN * FE * 4 + 114688 + ((size_t)NN * 3 + 1 + NE) * 4) return;

  const float* x   = (const float*)d_in[0];
  const int*   ei  = (const int*)d_in[1];
  const float* ea  = (const float*)d_in[2];
  const float* We1 = (const float*)d_in[3];
  const float* be1 = (const float*)d_in[4];
  const float* We2 = (const float*)d_in[5];
  const float* be2 = (const float*)d_in[6];
  const float* Wn1 = (const float*)d_in[7];
  const float* bn1 = (const float*)d_in[8];
  const float* Wn2 = (const float*)d_in[9];
  const float* bn2 = (const float*)d_in[10];

  float* xout = (float*)d_out;
  float* eout = xout + (size_t)NN * FN;

  float* agg = (float*)d_ws;                     // [NN*FE] f32, 16B-aligned
  unsigned short* P   = (unsigned short*)(agg + (size_t)NN * FE);
  unsigned short* Pe1 = P;              // 6*8*64*8  = 24576 shorts
  unsigned short* Pe2 = P + 24576;      // 4*4*64*8  =  8192
  unsigned short* Pn1 = P + 32768;      // 4*8*64*8  = 16384
  unsigned short* Pn2 = P + 49152;      //             8192
  int* cnt_i = (int*)(P + 57344);       // [NN]
  int* off   = cnt_i + NN;              // [NN+1]
  int* cur   = off + NN + 1;            // [NN]
  int* eidx  = cur + NN;                // [NE]

  zero_kernel<<<(NN * FE + 255) / 256, 256, 0, stream>>>(agg, NN * FE);
  zeroi_kernel<<<(NN + 255) / 256, 256, 0, stream>>>(cnt_i, NN);
  hist_kernel<<<(NE + 255) / 256, 256, 0, stream>>>(ei, cnt_i);
  scan_kernel<<<1, 256, 0, stream>>>(cnt_i, off, cur);
  scatter_kernel<<<(NE + 255) / 256, 256, 0, stream>>>(ei, cur, eidx);
  pack_w<<<(3072 + 255) / 256, 256, 0, stream>>>(We1, Pe1, HID, 3072);
  pack_w<<<(1024 + 255) / 256, 256, 0, stream>>>(We2, Pe2, FE, 1024);
  pack_w<<<(2048 + 255) / 256, 256, 0, stream>>>(Wn1, Pn1, HID, 2048);
  pack_w<<<(1024 + 255) / 256, 256, 0, stream>>>(Wn2, Pn2, FN, 1024);
  edge_mlp<<<NE / 64, 256, 0, stream>>>(x, ei, ea, eidx, Pe1, be1, Pe2, be2, eout, agg);
  node_mlp<<<(NN + 63) / 64, 256, 0, stream>>>(x, agg, cnt_i, Pn1, bn1, Pn2, bn2, xout);
}

// Round 11
// 304.705 us; speedup vs baseline: 1.3813x; 1.3813x over previous
//
#include <hip/hip_runtime.h>

// MetaLayer: edge MLP + mean-aggregate + node MLP. fp32 in/out, int32 idx.
// Ledger (R8-R10): pure edge MLP=158us; aggregation as 51M fp32 atomics=+110us
// (R8,total 333); as node CSR gather=+180+75us (R9,415); as sorted scatter=
// +50+75us (R10,420). R11: back to R8 streaming structure, but aggregation via
// global_atomic_pk_add_bf16 (packed col-pairs via shfl_xor) -> 25.6M ops,
// ~100MB write-through. agg stored bf16; node scales by 1/cnt on read. No CSR.

typedef __attribute__((ext_vector_type(8))) short bf16x8;   // MFMA A/B frag
typedef __attribute__((ext_vector_type(4))) float f4;       // MFMA C/D frag
typedef __attribute__((ext_vector_type(8))) unsigned short us8;
typedef __attribute__((ext_vector_type(4))) unsigned short us4;

constexpr int NN  = 50000;
constexpr int NE  = 800000;
constexpr int FN  = 64;
constexpr int FE  = 64;
constexpr int HID = 128;
constexpr int K1  = 2 * FN + FE; // 192
constexpr int K2  = FN + FE;     // 128

__device__ __forceinline__ float b2f(unsigned short u) {
  union { unsigned int i; float f; } v; v.i = ((unsigned int)u) << 16; return v.f;
}
__device__ __forceinline__ unsigned short f2b(float f) {
  union { float f; unsigned int i; } v; v.f = f;
  unsigned int r = v.i + 0x7FFFu + ((v.i >> 16) & 1u);
  return (unsigned short)(r >> 16);
}
__device__ __forceinline__ void cvt16(const f4* __restrict__ p, unsigned short* dst) {
  f4 a = p[0], b = p[1], c = p[2], d = p[3];
  us8 o0, o1;
#pragma unroll
  for (int j = 0; j < 4; j++) {
    o0[j] = f2b(a[j]); o0[4 + j] = f2b(b[j]);
    o1[j] = f2b(c[j]); o1[4 + j] = f2b(d[j]);
  }
  *(us8*)dst = o0; *(us8*)(dst + 8) = o1;
}
__device__ __forceinline__ f4 MF(bf16x8 a, bf16x8 b, f4 c) {
  return __builtin_amdgcn_mfma_f32_16x16x32_bf16(a, b, c, 0, 0, 0);
}
// packed bf16 atomic add (gfx940+/gfx950): mem[15:0]+=data[15:0], mem[31:16]+=data[31:16]
__device__ __forceinline__ void pk_atomic_add_bf16(unsigned short* addr, unsigned int data) {
  asm volatile("global_atomic_pk_add_bf16 %0, %1, off" :: "v"(addr), "v"(data) : "memory");
}

__global__ void zeroi_kernel(unsigned int* __restrict__ p, int n) {
  int i = blockIdx.x * 256 + threadIdx.x;
  if (i < n) p[i] = 0u;
}

__global__ void cnt_kernel(const int* __restrict__ ei, float* __restrict__ cnt) {
  int e = blockIdx.x * 256 + threadIdx.x;
  if (e < NE) atomicAdd(&cnt[ei[NE + e]], 1.0f);
}

// pack W[K][N] fp32 -> frag order [kstep][ntile][lane][8] bf16.
__global__ void pack_w(const float* __restrict__ W, unsigned short* __restrict__ P,
                       int N, int total) {
  int idx = blockIdx.x * 256 + threadIdx.x;
  if (idx >= total) return;
  const int l  = idx & 63;
  const int nt = (idx >> 6) % (N >> 4);
  const int s  = idx / ((N >> 4) << 6);
  const int col = nt * 16 + (l & 15);
  const int k0  = s * 32 + (l >> 4) * 8;
  us8 o;
#pragma unroll
  for (int j = 0; j < 8; j++) o[j] = f2b(W[(size_t)(k0 + j) * N + col]);
  *(us8*)(P + (size_t)idx * 8) = o;
}

// ---- edge MLP (MFMA): 64 edges/block (streaming order), 4 waves.
// sH aliases sA. Aggregation: packed-bf16 atomics (col pairs via shfl_xor).
__global__ __launch_bounds__(256) void edge_mlp(
    const float* __restrict__ x, const int* __restrict__ ei,
    const float* __restrict__ ea,
    const unsigned short* __restrict__ P1, const float* __restrict__ be1,
    const unsigned short* __restrict__ P2, const float* __restrict__ be2,
    float* __restrict__ eout, unsigned short* __restrict__ aggb) {
  __shared__ unsigned short sA[64][200]; // 25.6KB; 400B stride
  __shared__ int sC[64];
  unsigned short (*sH)[136] = (unsigned short(*)[136])&sA[0][0]; // alias
  const int tid = threadIdx.x;
  const int e0  = blockIdx.x * 64;

  { // stage gathered inputs -> bf16 LDS (4 threads/edge, 16 cols/segment)
    const int el = tid >> 2, q = tid & 3, ge = e0 + el;
    const int r = ei[ge], c = ei[NE + ge];
    if (q == 0) sC[el] = c;
    cvt16((const f4*)(x + (size_t)r * FN + q * 16), &sA[el][q * 16]);
    cvt16((const f4*)(x + (size_t)c * FN + q * 16), &sA[el][64 + q * 16]);
    cvt16((const f4*)(ea + (size_t)ge * FE + q * 16), &sA[el][128 + q * 16]);
  }
  __syncthreads();

  const int wave = tid >> 6, lane = tid & 63;
  const int mrow = lane & 15, kq = lane >> 4;

  // GEMM1: [64x192]@[192x128], wave -> ntiles {2w,2w+1}
  f4 acc[4][2];
#pragma unroll
  for (int m = 0; m < 4; m++) { acc[m][0] = (f4)0.f; acc[m][1] = (f4)0.f; }
  const int nt0 = wave * 2;
#pragma unroll
  for (int s = 0; s < 6; s++) {
    bf16x8 b0 = *(const bf16x8*)(P1 + (((size_t)s * 8 + nt0)     * 64 + lane) * 8);
    bf16x8 b1 = *(const bf16x8*)(P1 + (((size_t)s * 8 + nt0 + 1) * 64 + lane) * 8);
#pragma unroll
    for (int m = 0; m < 4; m++) {
      bf16x8 a = *(const bf16x8*)&sA[m * 16 + mrow][s * 32 + kq * 8];
      acc[m][0] = MF(a, b0, acc[m][0]);
      acc[m][1] = MF(a, b1, acc[m][1]);
    }
  }
  __syncthreads(); // sA reads done before alias overwrite

  { // bias + relu -> sH. D: row=(lane>>4)*4+i, col=lane&15
    const int c0 = nt0 * 16 + mrow, c1 = c0 + 16;
    const float bb0 = be1[c0], bb1 = be1[c1];
    const int rb = kq * 4;
#pragma unroll
    for (int m = 0; m < 4; m++)
#pragma unroll
      for (int i = 0; i < 4; i++) {
        sH[m * 16 + rb + i][c0] = f2b(fmaxf(acc[m][0][i] + bb0, 0.f));
        sH[m * 16 + rb + i][c1] = f2b(fmaxf(acc[m][1][i] + bb1, 0.f));
      }
  }
  __syncthreads();

  // GEMM2: [64x128]@[128x64], wave -> ntile w
  f4 a2[4];
#pragma unroll
  for (int m = 0; m < 4; m++) a2[m] = (f4)0.f;
#pragma unroll
  for (int s = 0; s < 4; s++) {
    bf16x8 b = *(const bf16x8*)(P2 + (((size_t)s * 4 + wave) * 64 + lane) * 8);
#pragma unroll
    for (int m = 0; m < 4; m++) {
      bf16x8 a = *(const bf16x8*)&sH[m * 16 + mrow][s * 32 + kq * 8];
      a2[m] = MF(a, b, a2[m]);
    }
  }
  { // epilogue: bias -> eout fp32; packed bf16 atomic agg (even lanes)
    const int col = wave * 16 + mrow;
    const float bb = be2[col];
    const int rb = kq * 4;
    const bool even = ((lane & 1) == 0);
#pragma unroll
    for (int m = 0; m < 4; m++)
#pragma unroll
      for (int i = 0; i < 4; i++) {
        const int er = m * 16 + rb + i;
        const float v = a2[m][i] + bb;
        eout[(size_t)(e0 + er) * FE + col] = v;
        const float vp = __shfl_xor(v, 1); // partner col (col^1) value
        if (even) {
          const unsigned int pk =
              (unsigned int)f2b(v) | ((unsigned int)f2b(vp) << 16);
          pk_atomic_add_bf16(aggb + ((size_t)sC[er] * FE + col), pk);
        }
      }
  }
}

// ---- node MLP (MFMA): 64 nodes/block, 4 waves. bf16 agg read, scale by 1/cnt.
__global__ __launch_bounds__(256) void node_mlp(
    const float* __restrict__ x, const unsigned short* __restrict__ aggb,
    const float* __restrict__ cnt,
    const unsigned short* __restrict__ P1, const float* __restrict__ bn1,
    const unsigned short* __restrict__ P2, const float* __restrict__ bn2,
    float* __restrict__ xout) {
  __shared__ unsigned short sA[64][136]; // 17.4KB; 272B stride
  unsigned short (*sH)[136] = (unsigned short(*)[136])&sA[0][0]; // alias
  const int tid = threadIdx.x;
  const int n0  = blockIdx.x * 64;

  { // stage: 4 threads/node; q<2: x 32-col halves; q>=2: bf16 agg halves (mean)
    const int nl = tid >> 2, q = tid & 3;
    const int gn = n0 + nl;
    if (gn < NN) {
      if (q < 2) {
        cvt16((const f4*)(x + (size_t)gn * FN + q * 32),      &sA[nl][q * 32]);
        cvt16((const f4*)(x + (size_t)gn * FN + q * 32 + 16), &sA[nl][q * 32 + 16]);
      } else {
        const float inv = 1.0f / fmaxf(cnt[gn], 1.0f);
        const int q2 = q - 2;
        const us8* pa = (const us8*)(aggb + (size_t)gn * FE + q2 * 32);
#pragma unroll
        for (int seg = 0; seg < 4; seg++) {
          us8 a = pa[seg];
          us8 o;
#pragma unroll
          for (int j = 0; j < 8; j++) o[j] = f2b(b2f(a[j]) * inv);
          *(us8*)&sA[nl][64 + q2 * 32 + seg * 8] = o;
        }
      }
    } else {
      us8 z = (us8)0;
#pragma unroll
      for (int sgi = 0; sgi < 4; sgi++) *(us8*)&sA[nl][q * 32 + sgi * 8] = z;
    }
  }
  __syncthreads();

  const int wave = tid >> 6, lane = tid & 63;
  const int mrow = lane & 15, kq = lane >> 4;

  // GEMM1: [64x128]@[128x128]
  f4 acc[4][2];
#pragma unroll
  for (int m = 0; m < 4; m++) { acc[m][0] = (f4)0.f; acc[m][1] = (f4)0.f; }
  const int nt0 = wave * 2;
#pragma unroll
  for (int s = 0; s < 4; s++) {
    bf16x8 b0 = *(const bf16x8*)(P1 + (((size_t)s * 8 + nt0)     * 64 + lane) * 8);
    bf16x8 b1 = *(const bf16x8*)(P1 + (((size_t)s * 8 + nt0 + 1) * 64 + lane) * 8);
#pragma unroll
    for (int m = 0; m < 4; m++) {
      bf16x8 a = *(const bf16x8*)&sA[m * 16 + mrow][s * 32 + kq * 8];
      acc[m][0] = MF(a, b0, acc[m][0]);
      acc[m][1] = MF(a, b1, acc[m][1]);
    }
  }
  __syncthreads();

  {
    const int c0 = nt0 * 16 + mrow, c1 = c0 + 16;
    const float bb0 = bn1[c0], bb1 = bn1[c1];
    const int rb = kq * 4;
#pragma unroll
    for (int m = 0; m < 4; m++)
#pragma unroll
      for (int i = 0; i < 4; i++) {
        sH[m * 16 + rb + i][c0] = f2b(fmaxf(acc[m][0][i] + bb0, 0.f));
        sH[m * 16 + rb + i][c1] = f2b(fmaxf(acc[m][1][i] + bb1, 0.f));
      }
  }
  __syncthreads();

  // GEMM2: [64x128]@[128x64]
  f4 a2[4];
#pragma unroll
  for (int m = 0; m < 4; m++) a2[m] = (f4)0.f;
#pragma unroll
  for (int s = 0; s < 4; s++) {
    bf16x8 b = *(const bf16x8*)(P2 + (((size_t)s * 4 + wave) * 64 + lane) * 8);
#pragma unroll
    for (int m = 0; m < 4; m++) {
      bf16x8 a = *(const bf16x8*)&sH[m * 16 + mrow][s * 32 + kq * 8];
      a2[m] = MF(a, b, a2[m]);
    }
  }
  {
    const int col = wave * 16 + mrow;
    const float bb = bn2[col];
    const int rb = kq * 4;
#pragma unroll
    for (int m = 0; m < 4; m++)
#pragma unroll
      for (int i = 0; i < 4; i++) {
        const int gn = n0 + m * 16 + rb + i;
        if (gn < NN) xout[(size_t)gn * FN + col] = a2[m][i] + bb;
      }
  }
}

extern "C" void kernel_launch(void* const* d_in, const int* in_sizes, int n_in,
                              void* d_out, int out_size, void* d_ws, size_t ws_size,
                              hipStream_t stream) {
  if (n_in != 11) return;
  if (in_sizes[0] != NN * FN) return;
  if (in_sizes[1] != 2 * NE) return;
  if (in_sizes[2] != NE * FE) return;
  if (out_size != NN * FN + NE * FE) return;
  // ws: agg bf16 6.4MB + cnt 200KB + packed W 114.7KB
  if (ws_size < (size_t)NN * FE * 2 + (size_t)NN * 4 + 114688) return;

  const float* x   = (const float*)d_in[0];
  const int*   ei  = (const int*)d_in[1];
  const float* ea  = (const float*)d_in[2];
  const float* We1 = (const float*)d_in[3];
  const float* be1 = (const float*)d_in[4];
  const float* We2 = (const float*)d_in[5];
  const float* be2 = (const float*)d_in[6];
  const float* Wn1 = (const float*)d_in[7];
  const float* bn1 = (const float*)d_in[8];
  const float* Wn2 = (const float*)d_in[9];
  const float* bn2 = (const float*)d_in[10];

  float* xout = (float*)d_out;
  float* eout = xout + (size_t)NN * FN;

  unsigned short* aggb = (unsigned short*)d_ws;          // [NN*FE] bf16
  float* cnt = (float*)(aggb + (size_t)NN * FE);         // [NN] fp32
  unsigned short* P   = (unsigned short*)(cnt + NN);     // packed weights
  unsigned short* Pe1 = P;              // 6*8*64*8  = 24576 shorts
  unsigned short* Pe2 = P + 24576;      // 4*4*64*8  =  8192
  unsigned short* Pn1 = P + 32768;      // 4*8*64*8  = 16384
  unsigned short* Pn2 = P + 49152;      //             8192

  const int zi = (NN * FE) / 2 + NN;    // agg (uint pairs) + cnt, both 0-bits
  zeroi_kernel<<<(zi + 255) / 256, 256, 0, stream>>>((unsigned int*)d_ws, zi);
  cnt_kernel<<<(NE + 255) / 256, 256, 0, stream>>>(ei, cnt);
  pack_w<<<(3072 + 255) / 256, 256, 0, stream>>>(We1, Pe1, HID, 3072);
  pack_w<<<(1024 + 255) / 256, 256, 0, stream>>>(We2, Pe2, FE, 1024);
  pack_w<<<(2048 + 255) / 256, 256, 0, stream>>>(Wn1, Pn1, HID, 2048);
  pack_w<<<(1024 + 255) / 256, 256, 0, stream>>>(Wn2, Pn2, FN, 1024);
  edge_mlp<<<NE / 64, 256, 0, stream>>>(x, ei, ea, Pe1, be1, Pe2, be2, eout, aggb);
  node_mlp<<<(NN + 63) / 64, 256, 0, stream>>>(x, aggb, cnt, Pn1, bn1, Pn2, bn2, xout);
}